// Round 3
// baseline (153.471 us; speedup 1.0000x reference)
//
#include <hip/hip_runtime.h>
#include <hip/hip_cooperative_groups.h>
#include <hip/hip_bf16.h>
#include <math.h>

namespace cg = cooperative_groups;

// Problem constants: H=1024, E=48, R=32
#define Hh 1024
#define Ee 48
#define Rr 32
#define NTRIP (Ee*Ee*Rr)   // 73728
#define NROWS 128          // 48 A + 32 R + 48 B rows of T
#define FSc 32             // f-split (coop path)
#define FCNT 32            // Hh/FSc
#define HS 32              // h-split for phase 2
#define HRANGE 32          // Hh/HS
#define PITCH 36           // LDS row pitch: 36%32=4 -> 8 lane-groups hit 8 disjoint bank quads
#define SLOT_FLOATS (60*PITCH + HRANGE)   // 2192 floats per staging buffer

union F4 { float4 v; float f[4]; };

// ============================ fused cooperative kernel ============================
// grid 256 x block 256 (1 block/CU, co-resident). Three grid syncs replace three
// inter-kernel graph dependencies.
__global__ __launch_bounds__(256) void fused_all(
    const float* __restrict__ ent, const float* __restrict__ rel,
    const float* __restrict__ W1, const float* __restrict__ b1,
    const float* __restrict__ W2, const float* __restrict__ b2,
    const int* __restrict__ starts, const int* __restrict__ maxd,
    float* __restrict__ Ppart, float* __restrict__ T,
    float* __restrict__ Lpart, float* __restrict__ out)
{
    __shared__ float smem[2 * SLOT_FLOATS];   // 17.5 KB; reused across phases
    const int tid = threadIdx.x;
    const int b = blockIdx.x;
    cg::grid_group grid = cg::this_grid();

    // ---------------- phase 1: Ppart[fs][row][h] (16 rows x 1024 h x 32 K per block)
    {
        const int rt = b & 7;          // row-tile 0..7
        const int fs = b >> 3;         // f-slice 0..31
        const int row0 = rt * 16;

        const float* emb; int foff;
        if (row0 < 48)      { emb = ent + row0 * Hh;        foff = 0;      }
        else if (row0 < 80) { emb = rel + (row0 - 48) * Hh; foff = Hh;     }
        else                { emb = ent + (row0 - 80) * Hh; foff = 2 * Hh; }

        const int f0 = fs * FCNT;
        float* se = smem;                       // [16][FCNT] = 512 floats
        for (int idx = tid; idx < 16 * FCNT; idx += 256)
            se[idx] = emb[(idx >> 5) * Hh + f0 + (idx & 31)];
        __syncthreads();

        const float* w1base = W1 + (size_t)(foff + f0) * Hh + 4 * tid;

        float acc[16][4];
#pragma unroll
        for (int r = 0; r < 16; ++r)
#pragma unroll
            for (int c = 0; c < 4; ++c) acc[r][c] = 0.f;

        F4 wcur[4];
#pragma unroll
        for (int c = 0; c < 4; ++c)
            wcur[c].v = *reinterpret_cast<const float4*>(w1base + (size_t)c * Hh);

        for (int f = 0; f < FCNT; f += 4) {
            const int fn = (f + 4 < FCNT) ? f + 4 : f;
            F4 wnxt[4];
#pragma unroll
            for (int c = 0; c < 4; ++c)
                wnxt[c].v = *reinterpret_cast<const float4*>(w1base + (size_t)(fn + c) * Hh);
#pragma unroll
            for (int r = 0; r < 16; ++r) {
                F4 e4; e4.v = *reinterpret_cast<const float4*>(&se[r * FCNT + f]); // broadcast
#pragma unroll
                for (int ff = 0; ff < 4; ++ff) {
                    const float ev = e4.f[ff];
#pragma unroll
                    for (int c = 0; c < 4; ++c)
                        acc[r][c] = fmaf(ev, wcur[ff].f[c], acc[r][c]);
                }
            }
#pragma unroll
            for (int c = 0; c < 4; ++c) wcur[c] = wnxt[c];
        }

        float* outp = Ppart + ((size_t)fs * NROWS + row0) * Hh + 4 * tid;
#pragma unroll
        for (int r = 0; r < 16; ++r) {
            F4 o;
#pragma unroll
            for (int c = 0; c < 4; ++c) o.f[c] = acc[r][c];
            *reinterpret_cast<float4*>(outp + (size_t)r * Hh) = o.v;
        }
    }
    grid.sync();

    // ---------------- phase 1b: reduce f-slices into T, fold b1 into rel rows
    {
        for (int e = 0; e < 2; ++e) {
            const int idx = b * 512 + e * 256 + tid;     // < 131072
            float s = 0.f;
#pragma unroll
            for (int fs = 0; fs < FSc; ++fs) s += Ppart[(size_t)fs * (NROWS * Hh) + idx];
            const int r = idx >> 10, h = idx & 1023;
            if (r >= 48 && r < 80) s += b1[h];
            T[idx] = s;
        }
    }
    grid.sync();

    // ---------------- phase 2: triplet partial logits (768 slots, 3 per block,
    //                  double-buffered LDS staging)
    {
        const int wave = tid >> 6;
        const int lane = tid & 63;
        const int jG = lane & 7;
        const int kG = lane >> 3;

        float rr[8];

        auto load_slot = [&](int slot, float* r8) {
            const int it = slot % 12;
            const int jt = (slot / 12) & 1;
            const int z  = slot / 24;
            const int i0 = it * 4, j0 = jt * 24, h0 = z * HRANGE;
#pragma unroll
            for (int q = 0; q < 8; ++q) {
                const int idx = tid + q * 256;
                float v = 0.f;
                if (idx < 1920) {
                    const int rsel = idx >> 5, h = idx & 31;
                    int g;
                    if (rsel < 4)       g = i0 + rsel;             // A (subject)
                    else if (rsel < 36) g = 44 + rsel;             // R rows 48..79
                    else                g = 80 + j0 + (rsel - 36); // B (object)
                    v = T[g * Hh + h0 + h];
                } else if (idx < 1952) {
                    v = W2[h0 + (idx - 1920)];
                }
                r8[q] = v;
            }
        };

        auto write_slot = [&](float* buf, const float* r8) {
#pragma unroll
            for (int q = 0; q < 8; ++q) {
                const int idx = tid + q * 256;
                if (idx < 1920)       buf[(idx >> 5) * PITCH + (idx & 31)] = r8[q];
                else if (idx < 1952)  buf[60 * PITCH + (idx - 1920)] = r8[q];
            }
        };

        auto compute_store = [&](const float* sm, int slot) {
            const int it = slot % 12;
            const int jt = (slot / 12) & 1;
            const int z  = slot / 24;
            const int i0 = it * 4, j0 = jt * 24;

            const float* pa = sm + wave * PITCH;
            const float* pw = sm + 60 * PITCH;

            float acc[3][4];
#pragma unroll
            for (int a = 0; a < 3; ++a)
#pragma unroll
                for (int bb2 = 0; bb2 < 4; ++bb2) acc[a][bb2] = 0.f;

#pragma unroll
            for (int h4 = 0; h4 < HRANGE; h4 += 4) {
                F4 av, wv, rv[4], bv[3];
                av.v = *reinterpret_cast<const float4*>(pa + h4);
                wv.v = *reinterpret_cast<const float4*>(pw + h4);
#pragma unroll
                for (int tk = 0; tk < 4; ++tk)
                    rv[tk].v = *reinterpret_cast<const float4*>(sm + (4 + kG + 8 * tk) * PITCH + h4);
#pragma unroll
                for (int tj = 0; tj < 3; ++tj)
                    bv[tj].v = *reinterpret_cast<const float4*>(sm + (36 + jG + 8 * tj) * PITCH + h4);

#pragma unroll
                for (int c = 0; c < 4; ++c) {
                    const float a = av.f[c], w = wv.f[c];
                    float p[4];
#pragma unroll
                    for (int tk = 0; tk < 4; ++tk) p[tk] = a + rv[tk].f[c];
#pragma unroll
                    for (int tj = 0; tj < 3; ++tj) {
                        const float bb = bv[tj].f[c];
#pragma unroll
                        for (int tk = 0; tk < 4; ++tk) {
                            float v = p[tk] + bb;
                            v = v > 0.f ? v : 0.f;
                            acc[tj][tk] = fmaf(v, w, acc[tj][tk]);
                        }
                    }
                }
            }

            float* lp = Lpart + (size_t)z * NTRIP;
            const int i_ = i0 + wave;
#pragma unroll
            for (int tj = 0; tj < 3; ++tj) {
                const int j_ = j0 + jG + 8 * tj;
#pragma unroll
                for (int tk = 0; tk < 4; ++tk) {
                    const int k_ = kG + 8 * tk;
                    lp[(i_ * Ee + j_) * Rr + k_] = acc[tj][tk];
                }
            }
        };

        load_slot(b, rr);
        write_slot(smem, rr);
        __syncthreads();
        for (int s = 0; s < 3; ++s) {
            if (s < 2) load_slot(b + (s + 1) * 256, rr);   // prefetch next slot (global->reg)
            compute_store(smem + (s & 1) * SLOT_FLOATS, b + s * 256);
            if (s < 2) {
                __syncthreads();
                write_slot(smem + ((s + 1) & 1) * SLOT_FLOATS, rr);
                __syncthreads();
            }
        }
    }
    grid.sync();

    // ---------------- phase 3: reduce h-slices, sigmoid, mask
    {
        const int maxdv = maxd[0];
        const float bias2 = b2[0];
#pragma unroll
        for (int e = 0; e < 2; ++e) {
            const int idx = b * 256 + tid + e * 65536;
            if (idx < NTRIP) {
                float s = bias2;
#pragma unroll
                for (int z = 0; z < HS; ++z) s += Lpart[(size_t)z * NTRIP + idx];
                const int ij = idx >> 5;
                const int j = ij % Ee;
                const int i = ij / Ee;
                const float sc = 1.f / (1.f + expf(-s));
                int di = starts[i] - starts[j]; if (di < 0) di = -di;
                out[idx] = (i != j && di <= maxdv) ? sc : 0.f;
            }
        }
    }
}

// ============================ legacy fallback (round-2 path) ============================
__global__ __launch_bounds__(256) void k1_gemm(const float* __restrict__ ent,
                                               const float* __restrict__ rel,
                                               const float* __restrict__ W1,
                                               float* __restrict__ Ppart,
                                               int fcount) {
    extern __shared__ float se[];
    const int rt = blockIdx.x;
    const int fs = blockIdx.y;
    const int row0 = rt * 16;
    const int tid = threadIdx.x;

    const float* emb; int foff;
    if (row0 < 48)      { emb = ent + row0 * Hh;        foff = 0;      }
    else if (row0 < 80) { emb = rel + (row0 - 48) * Hh; foff = Hh;     }
    else                { emb = ent + (row0 - 80) * Hh; foff = 2 * Hh; }

    const int f0 = fs * fcount;
    for (int idx = tid; idx < 16 * fcount; idx += 256) {
        const int r = idx / fcount, f = idx % fcount;
        se[idx] = emb[r * Hh + f0 + f];
    }
    __syncthreads();

    const float* w1base = W1 + (size_t)(foff + f0) * Hh + 4 * tid;
    float acc[16][4];
#pragma unroll
    for (int r = 0; r < 16; ++r)
#pragma unroll
        for (int c = 0; c < 4; ++c) acc[r][c] = 0.f;

    F4 wcur[4];
#pragma unroll
    for (int c = 0; c < 4; ++c)
        wcur[c].v = *reinterpret_cast<const float4*>(w1base + (size_t)c * Hh);

    for (int f = 0; f < fcount; f += 4) {
        const int fn = (f + 4 < fcount) ? f + 4 : f;
        F4 wnxt[4];
#pragma unroll
        for (int c = 0; c < 4; ++c)
            wnxt[c].v = *reinterpret_cast<const float4*>(w1base + (size_t)(fn + c) * Hh);
#pragma unroll
        for (int r = 0; r < 16; ++r) {
            F4 e4; e4.v = *reinterpret_cast<const float4*>(&se[r * fcount + f]);
#pragma unroll
            for (int ff = 0; ff < 4; ++ff) {
                const float ev = e4.f[ff];
#pragma unroll
                for (int c = 0; c < 4; ++c)
                    acc[r][c] = fmaf(ev, wcur[ff].f[c], acc[r][c]);
            }
        }
#pragma unroll
        for (int c = 0; c < 4; ++c) wcur[c] = wnxt[c];
    }

    float* outp = Ppart + ((size_t)fs * NROWS + row0) * Hh + 4 * tid;
#pragma unroll
    for (int r = 0; r < 16; ++r) {
        F4 o;
#pragma unroll
        for (int c = 0; c < 4; ++c) o.f[c] = acc[r][c];
        *reinterpret_cast<float4*>(outp + (size_t)r * Hh) = o.v;
    }
}

__global__ __launch_bounds__(256) void k1b_reduce(const float* __restrict__ Ppart,
                                                  const float* __restrict__ b1,
                                                  float* __restrict__ T, int FS) {
    const int idx = blockIdx.x * 256 + threadIdx.x;
    const int r = idx >> 10, h = idx & 1023;
    float s = 0.f;
    for (int fs = 0; fs < FS; ++fs) s += Ppart[(size_t)fs * (NROWS * Hh) + idx];
    if (r >= 48 && r < 80) s += b1[h];
    T[idx] = s;
}

__global__ __launch_bounds__(256) void k2_triplets(const float* __restrict__ T,
                                                   const float* __restrict__ W2,
                                                   float* __restrict__ Lpart) {
    __shared__ float sm[60 * PITCH + HRANGE];
    const int tid = threadIdx.x;
    const int i0 = blockIdx.x * 4;
    const int j0 = blockIdx.y * 24;
    const int h0 = blockIdx.z * HRANGE;

    for (int idx = tid; idx < 60 * HRANGE; idx += 256) {
        const int rsel = idx >> 5;
        const int h = idx & (HRANGE - 1);
        int g;
        if (rsel < 4)       g = i0 + rsel;
        else if (rsel < 36) g = 48 + (rsel - 4);
        else                g = 80 + j0 + (rsel - 36);
        sm[rsel * PITCH + h] = T[g * Hh + h0 + h];
    }
    if (tid < HRANGE) sm[60 * PITCH + tid] = W2[h0 + tid];
    __syncthreads();

    const int wave = tid >> 6;
    const int lane = tid & 63;
    const int jG = lane & 7;
    const int kG = lane >> 3;

    const float* pa = sm + wave * PITCH;
    const float* pw = sm + 60 * PITCH;

    float acc[3][4];
#pragma unroll
    for (int a = 0; a < 3; ++a)
#pragma unroll
        for (int bb = 0; bb < 4; ++bb) acc[a][bb] = 0.f;

#pragma unroll
    for (int h4 = 0; h4 < HRANGE; h4 += 4) {
        F4 av, wv, rv[4], bv[3];
        av.v = *reinterpret_cast<const float4*>(pa + h4);
        wv.v = *reinterpret_cast<const float4*>(pw + h4);
#pragma unroll
        for (int tk = 0; tk < 4; ++tk)
            rv[tk].v = *reinterpret_cast<const float4*>(sm + (4 + kG + 8 * tk) * PITCH + h4);
#pragma unroll
        for (int tj = 0; tj < 3; ++tj)
            bv[tj].v = *reinterpret_cast<const float4*>(sm + (36 + jG + 8 * tj) * PITCH + h4);

#pragma unroll
        for (int c = 0; c < 4; ++c) {
            const float a = av.f[c], w = wv.f[c];
            float p[4];
#pragma unroll
            for (int tk = 0; tk < 4; ++tk) p[tk] = a + rv[tk].f[c];
#pragma unroll
            for (int tj = 0; tj < 3; ++tj) {
                const float bb = bv[tj].f[c];
#pragma unroll
                for (int tk = 0; tk < 4; ++tk) {
                    float v = p[tk] + bb;
                    v = v > 0.f ? v : 0.f;
                    acc[tj][tk] = fmaf(v, w, acc[tj][tk]);
                }
            }
        }
    }

    float* lp = Lpart + (size_t)blockIdx.z * NTRIP;
    const int i_ = i0 + wave;
#pragma unroll
    for (int tj = 0; tj < 3; ++tj) {
        const int j_ = j0 + jG + 8 * tj;
#pragma unroll
        for (int tk = 0; tk < 4; ++tk) {
            const int k_ = kG + 8 * tk;
            lp[(i_ * Ee + j_) * Rr + k_] = acc[tj][tk];
        }
    }
}

__global__ __launch_bounds__(256) void k3_final(const float* __restrict__ Lpart,
                                                const float* __restrict__ b2,
                                                const int* __restrict__ starts,
                                                const int* __restrict__ maxd,
                                                float* __restrict__ out) {
    const int idx = blockIdx.x * 256 + threadIdx.x;
    float s = b2[0];
#pragma unroll
    for (int z = 0; z < HS; ++z) s += Lpart[(size_t)z * NTRIP + idx];
    const int ij = idx >> 5;
    const int j = ij % Ee;
    const int i = ij / Ee;
    const float sc = 1.f / (1.f + expf(-s));
    int di = starts[i] - starts[j]; if (di < 0) di = -di;
    const bool m = (i != j) && (di <= maxd[0]);
    out[idx] = m ? sc : 0.f;
}

// ============================ launch ============================
extern "C" void kernel_launch(void* const* d_in, const int* in_sizes, int n_in,
                              void* d_out, int out_size, void* d_ws, size_t ws_size,
                              hipStream_t stream) {
    const float* ent    = (const float*)d_in[0];
    const float* rel    = (const float*)d_in[1];
    const float* W1     = (const float*)d_in[2];
    const float* b1     = (const float*)d_in[3];
    const float* W2     = (const float*)d_in[4];
    const float* b2     = (const float*)d_in[5];
    const int*   starts = (const int*)d_in[6];
    const int*   maxd   = (const int*)d_in[7];
    float* out = (float*)d_out;
    char* ws = (char*)d_ws;

    const size_t ppartB = (size_t)FSc * NROWS * Hh * 4;      // 16.78 MB (> Lpart 9.44 MB)
    const size_t tB = (size_t)NROWS * Hh * 4;                // 0.52 MB

    if (ws_size >= ppartB + tB) {
        float* Ppart = (float*)ws;
        float* Lpart = (float*)ws;                  // reuses Ppart region after phase 1b
        float* T     = (float*)(ws + ppartB);

        void* args[] = { (void*)&ent, (void*)&rel, (void*)&W1, (void*)&b1,
                         (void*)&W2, (void*)&b2, (void*)&starts, (void*)&maxd,
                         (void*)&Ppart, (void*)&T, (void*)&Lpart, (void*)&out };
        hipLaunchCooperativeKernel((const void*)fused_all, dim3(256), dim3(256),
                                   args, 0, stream);
    } else {
        // legacy 4-kernel fallback for small workspaces
        const size_t lpartB = (size_t)HS * NTRIP * 4;
        int FS = 8;
        while (FS > 2) {
            const size_t pB = (size_t)FS * NROWS * Hh * 4;
            const size_t regionA = (pB > lpartB) ? pB : lpartB;
            if (regionA + tB <= ws_size) break;
            FS >>= 1;
        }
        const size_t pB = (size_t)FS * NROWS * Hh * 4;
        const size_t regionA = (pB > lpartB) ? pB : lpartB;

        float* Ppart = (float*)ws;
        float* Lpart = (float*)ws;
        float* T     = (float*)(ws + regionA);

        const int fcount = Hh / FS;
        k1_gemm<<<dim3(8, FS), 256, 16 * fcount * 4, stream>>>(ent, rel, W1, Ppart, fcount);
        k1b_reduce<<<(NROWS * Hh) / 256, 256, 0, stream>>>(Ppart, b1, T, FS);
        k2_triplets<<<dim3(12, 2, HS), 256, 0, stream>>>(T, W2, Lpart);
        k3_final<<<NTRIP / 256, 256, 0, stream>>>(Lpart, b2, starts, maxd, out);
    }
}

// Round 4
// 121.671 us; speedup vs baseline: 1.2614x; 1.2614x over previous
//
#include <hip/hip_runtime.h>
#include <hip/hip_bf16.h>
#include <math.h>

// Problem constants: H=1024, E=48, R=32
#define Hh 1024
#define Ee 48
#define Rr 32
#define NTRIP (Ee*Ee*Rr)   // 73728
#define NROWS 128          // 48 A + 32 R + 48 B rows of T
#define FSc 32             // f-split (fused path)
#define FCNT 32            // Hh/FSc
#define HS 32              // h-split for phase 2
#define HRANGE 32          // Hh/HS
#define PITCH 36           // LDS row pitch: 36%32=4 -> 8 lane-groups on disjoint bank quads
#define SLOT_FLOATS (60*PITCH + HRANGE)   // 2192 floats per staging buffer

union F4 { float4 v; float f[4]; };

// -------- hand-rolled global barrier (all 256 blocks co-resident by construction)
__device__ __forceinline__ void gbar(unsigned* cnt, unsigned tgt) {
    __syncthreads();
    if (threadIdx.x == 0) {
        __threadfence();                     // release: make my global writes visible
        atomicAdd(cnt, 1u);                  // device-scope by default on CDNA
        while (__hip_atomic_load(cnt, __ATOMIC_RELAXED, __HIP_MEMORY_SCOPE_AGENT) < tgt)
            __builtin_amdgcn_s_sleep(2);
        __threadfence();                     // acquire: invalidate L1 before reading others' data
    }
    __syncthreads();
}

// ============================ fused kernel with SW barriers ============================
// grid 256 x block 256 (<=2 blocks/CU worst case -> always co-resident).
__global__ __launch_bounds__(256) void fused_bar(
    const float* __restrict__ ent, const float* __restrict__ rel,
    const float* __restrict__ W1, const float* __restrict__ b1,
    const float* __restrict__ W2, const float* __restrict__ b2,
    const int* __restrict__ starts, const int* __restrict__ maxd,
    float* __restrict__ Ppart, float* __restrict__ T,
    float* __restrict__ Lpart, float* __restrict__ out,
    unsigned* __restrict__ cnt)
{
    __shared__ float smem[2 * SLOT_FLOATS];   // 17.5 KB; reused across phases
    const int tid = threadIdx.x;
    const int b = blockIdx.x;

    // ---------------- phase 1: Ppart[fs][row][h] (16 rows x 1024 h x 32 K per block)
    {
        const int rt = b & 7;          // row-tile 0..7
        const int fs = b >> 3;         // f-slice 0..31
        const int row0 = rt * 16;

        const float* emb; int foff;
        if (row0 < 48)      { emb = ent + row0 * Hh;        foff = 0;      }
        else if (row0 < 80) { emb = rel + (row0 - 48) * Hh; foff = Hh;     }
        else                { emb = ent + (row0 - 80) * Hh; foff = 2 * Hh; }

        const int f0 = fs * FCNT;
        float* se = smem;                       // [16][FCNT] = 512 floats
        for (int idx = tid; idx < 16 * FCNT; idx += 256)
            se[idx] = emb[(idx >> 5) * Hh + f0 + (idx & 31)];
        __syncthreads();

        const float* w1base = W1 + (size_t)(foff + f0) * Hh + 4 * tid;

        float acc[16][4];
#pragma unroll
        for (int r = 0; r < 16; ++r)
#pragma unroll
            for (int c = 0; c < 4; ++c) acc[r][c] = 0.f;

        F4 wcur[4];
#pragma unroll
        for (int c = 0; c < 4; ++c)
            wcur[c].v = *reinterpret_cast<const float4*>(w1base + (size_t)c * Hh);

        for (int f = 0; f < FCNT; f += 4) {
            const int fn = (f + 4 < FCNT) ? f + 4 : f;
            F4 wnxt[4];
#pragma unroll
            for (int c = 0; c < 4; ++c)
                wnxt[c].v = *reinterpret_cast<const float4*>(w1base + (size_t)(fn + c) * Hh);
#pragma unroll
            for (int r = 0; r < 16; ++r) {
                F4 e4; e4.v = *reinterpret_cast<const float4*>(&se[r * FCNT + f]); // broadcast
#pragma unroll
                for (int ff = 0; ff < 4; ++ff) {
                    const float ev = e4.f[ff];
#pragma unroll
                    for (int c = 0; c < 4; ++c)
                        acc[r][c] = fmaf(ev, wcur[ff].f[c], acc[r][c]);
                }
            }
#pragma unroll
            for (int c = 0; c < 4; ++c) wcur[c] = wnxt[c];
        }

        float* outp = Ppart + ((size_t)fs * NROWS + row0) * Hh + 4 * tid;
#pragma unroll
        for (int r = 0; r < 16; ++r) {
            F4 o;
#pragma unroll
            for (int c = 0; c < 4; ++c) o.f[c] = acc[r][c];
            *reinterpret_cast<float4*>(outp + (size_t)r * Hh) = o.v;
        }
    }
    gbar(cnt, 256);

    // ---------------- phase 1b: reduce f-slices into T, fold b1 into rel rows
    {
        for (int e = 0; e < 2; ++e) {
            const int idx = b * 512 + e * 256 + tid;     // < 131072
            float s = 0.f;
#pragma unroll
            for (int fs = 0; fs < FSc; ++fs) s += Ppart[(size_t)fs * (NROWS * Hh) + idx];
            const int r = idx >> 10, h = idx & 1023;
            if (r >= 48 && r < 80) s += b1[h];
            T[idx] = s;
        }
    }
    gbar(cnt, 512);

    // ---------------- phase 2: triplet partial logits (768 slots, 3 per block)
    {
        const int wave = tid >> 6;
        const int lane = tid & 63;
        const int jG = lane & 7;
        const int kG = lane >> 3;

        float rr[8];

        auto load_slot = [&](int slot, float* r8) {
            const int it = slot % 12;
            const int jt = (slot / 12) & 1;
            const int z  = slot / 24;
            const int i0 = it * 4, j0 = jt * 24, h0 = z * HRANGE;
#pragma unroll
            for (int q = 0; q < 8; ++q) {
                const int idx = tid + q * 256;
                float v = 0.f;
                if (idx < 1920) {
                    const int rsel = idx >> 5, h = idx & 31;
                    int g;
                    if (rsel < 4)       g = i0 + rsel;             // A (subject)
                    else if (rsel < 36) g = 44 + rsel;             // R rows 48..79
                    else                g = 80 + j0 + (rsel - 36); // B (object)
                    v = T[g * Hh + h0 + h];
                } else if (idx < 1952) {
                    v = W2[h0 + (idx - 1920)];
                }
                r8[q] = v;
            }
        };

        auto write_slot = [&](float* buf, const float* r8) {
#pragma unroll
            for (int q = 0; q < 8; ++q) {
                const int idx = tid + q * 256;
                if (idx < 1920)       buf[(idx >> 5) * PITCH + (idx & 31)] = r8[q];
                else if (idx < 1952)  buf[60 * PITCH + (idx - 1920)] = r8[q];
            }
        };

        auto compute_store = [&](const float* sm, int slot) {
            const int it = slot % 12;
            const int jt = (slot / 12) & 1;
            const int z  = slot / 24;
            const int i0 = it * 4, j0 = jt * 24;

            const float* pa = sm + wave * PITCH;
            const float* pw = sm + 60 * PITCH;

            float acc[3][4];
#pragma unroll
            for (int a = 0; a < 3; ++a)
#pragma unroll
                for (int bb2 = 0; bb2 < 4; ++bb2) acc[a][bb2] = 0.f;

#pragma unroll
            for (int h4 = 0; h4 < HRANGE; h4 += 4) {
                F4 av, wv, rv[4], bv[3];
                av.v = *reinterpret_cast<const float4*>(pa + h4);
                wv.v = *reinterpret_cast<const float4*>(pw + h4);
#pragma unroll
                for (int tk = 0; tk < 4; ++tk)
                    rv[tk].v = *reinterpret_cast<const float4*>(sm + (4 + kG + 8 * tk) * PITCH + h4);
#pragma unroll
                for (int tj = 0; tj < 3; ++tj)
                    bv[tj].v = *reinterpret_cast<const float4*>(sm + (36 + jG + 8 * tj) * PITCH + h4);

#pragma unroll
                for (int c = 0; c < 4; ++c) {
                    const float a = av.f[c], w = wv.f[c];
                    float p[4];
#pragma unroll
                    for (int tk = 0; tk < 4; ++tk) p[tk] = a + rv[tk].f[c];
#pragma unroll
                    for (int tj = 0; tj < 3; ++tj) {
                        const float bb = bv[tj].f[c];
#pragma unroll
                        for (int tk = 0; tk < 4; ++tk) {
                            float v = p[tk] + bb;
                            v = v > 0.f ? v : 0.f;
                            acc[tj][tk] = fmaf(v, w, acc[tj][tk]);
                        }
                    }
                }
            }

            float* lp = Lpart + (size_t)z * NTRIP;
            const int i_ = i0 + wave;
#pragma unroll
            for (int tj = 0; tj < 3; ++tj) {
                const int j_ = j0 + jG + 8 * tj;
#pragma unroll
                for (int tk = 0; tk < 4; ++tk) {
                    const int k_ = kG + 8 * tk;
                    lp[(i_ * Ee + j_) * Rr + k_] = acc[tj][tk];
                }
            }
        };

        load_slot(b, rr);
        write_slot(smem, rr);
        __syncthreads();
        for (int s = 0; s < 3; ++s) {
            if (s < 2) load_slot(b + (s + 1) * 256, rr);   // prefetch next slot (global->reg)
            compute_store(smem + (s & 1) * SLOT_FLOATS, b + s * 256);
            if (s < 2) {
                __syncthreads();
                write_slot(smem + ((s + 1) & 1) * SLOT_FLOATS, rr);
                __syncthreads();
            }
        }
    }
    gbar(cnt, 768);

    // ---------------- phase 3: reduce h-slices, sigmoid, mask
    {
        const int maxdv = maxd[0];
        const float bias2 = b2[0];
#pragma unroll
        for (int e = 0; e < 2; ++e) {
            const int idx = b * 256 + tid + e * 65536;
            if (idx < NTRIP) {
                float s = bias2;
#pragma unroll
                for (int z = 0; z < HS; ++z) s += Lpart[(size_t)z * NTRIP + idx];
                const int ij = idx >> 5;
                const int j = ij % Ee;
                const int i = ij / Ee;
                const float sc = 1.f / (1.f + expf(-s));
                int di = starts[i] - starts[j]; if (di < 0) di = -di;
                out[idx] = (i != j && di <= maxdv) ? sc : 0.f;
            }
        }
    }
}

// ============================ legacy fallback (round-2 path) ============================
__global__ __launch_bounds__(256) void k1_gemm(const float* __restrict__ ent,
                                               const float* __restrict__ rel,
                                               const float* __restrict__ W1,
                                               float* __restrict__ Ppart,
                                               int fcount) {
    extern __shared__ float se[];
    const int rt = blockIdx.x;
    const int fs = blockIdx.y;
    const int row0 = rt * 16;
    const int tid = threadIdx.x;

    const float* emb; int foff;
    if (row0 < 48)      { emb = ent + row0 * Hh;        foff = 0;      }
    else if (row0 < 80) { emb = rel + (row0 - 48) * Hh; foff = Hh;     }
    else                { emb = ent + (row0 - 80) * Hh; foff = 2 * Hh; }

    const int f0 = fs * fcount;
    for (int idx = tid; idx < 16 * fcount; idx += 256) {
        const int r = idx / fcount, f = idx % fcount;
        se[idx] = emb[r * Hh + f0 + f];
    }
    __syncthreads();

    const float* w1base = W1 + (size_t)(foff + f0) * Hh + 4 * tid;
    float acc[16][4];
#pragma unroll
    for (int r = 0; r < 16; ++r)
#pragma unroll
        for (int c = 0; c < 4; ++c) acc[r][c] = 0.f;

    F4 wcur[4];
#pragma unroll
    for (int c = 0; c < 4; ++c)
        wcur[c].v = *reinterpret_cast<const float4*>(w1base + (size_t)c * Hh);

    for (int f = 0; f < fcount; f += 4) {
        const int fn = (f + 4 < fcount) ? f + 4 : f;
        F4 wnxt[4];
#pragma unroll
        for (int c = 0; c < 4; ++c)
            wnxt[c].v = *reinterpret_cast<const float4*>(w1base + (size_t)(fn + c) * Hh);
#pragma unroll
        for (int r = 0; r < 16; ++r) {
            F4 e4; e4.v = *reinterpret_cast<const float4*>(&se[r * fcount + f]);
#pragma unroll
            for (int ff = 0; ff < 4; ++ff) {
                const float ev = e4.f[ff];
#pragma unroll
                for (int c = 0; c < 4; ++c)
                    acc[r][c] = fmaf(ev, wcur[ff].f[c], acc[r][c]);
            }
        }
#pragma unroll
        for (int c = 0; c < 4; ++c) wcur[c] = wnxt[c];
    }

    float* outp = Ppart + ((size_t)fs * NROWS + row0) * Hh + 4 * tid;
#pragma unroll
    for (int r = 0; r < 16; ++r) {
        F4 o;
#pragma unroll
        for (int c = 0; c < 4; ++c) o.f[c] = acc[r][c];
        *reinterpret_cast<float4*>(outp + (size_t)r * Hh) = o.v;
    }
}

__global__ __launch_bounds__(256) void k1b_reduce(const float* __restrict__ Ppart,
                                                  const float* __restrict__ b1,
                                                  float* __restrict__ T, int FS) {
    const int idx = blockIdx.x * 256 + threadIdx.x;
    const int r = idx >> 10, h = idx & 1023;
    float s = 0.f;
    for (int fs = 0; fs < FS; ++fs) s += Ppart[(size_t)fs * (NROWS * Hh) + idx];
    if (r >= 48 && r < 80) s += b1[h];
    T[idx] = s;
}

__global__ __launch_bounds__(256) void k2_triplets(const float* __restrict__ T,
                                                   const float* __restrict__ W2,
                                                   float* __restrict__ Lpart) {
    __shared__ float sm[60 * PITCH + HRANGE];
    const int tid = threadIdx.x;
    const int i0 = blockIdx.x * 4;
    const int j0 = blockIdx.y * 24;
    const int h0 = blockIdx.z * HRANGE;

    for (int idx = tid; idx < 60 * HRANGE; idx += 256) {
        const int rsel = idx >> 5;
        const int h = idx & (HRANGE - 1);
        int g;
        if (rsel < 4)       g = i0 + rsel;
        else if (rsel < 36) g = 48 + (rsel - 4);
        else                g = 80 + j0 + (rsel - 36);
        sm[rsel * PITCH + h] = T[g * Hh + h0 + h];
    }
    if (tid < HRANGE) sm[60 * PITCH + tid] = W2[h0 + tid];
    __syncthreads();

    const int wave = tid >> 6;
    const int lane = tid & 63;
    const int jG = lane & 7;
    const int kG = lane >> 3;

    const float* pa = sm + wave * PITCH;
    const float* pw = sm + 60 * PITCH;

    float acc[3][4];
#pragma unroll
    for (int a = 0; a < 3; ++a)
#pragma unroll
        for (int bb = 0; bb < 4; ++bb) acc[a][bb] = 0.f;

#pragma unroll
    for (int h4 = 0; h4 < HRANGE; h4 += 4) {
        F4 av, wv, rv[4], bv[3];
        av.v = *reinterpret_cast<const float4*>(pa + h4);
        wv.v = *reinterpret_cast<const float4*>(pw + h4);
#pragma unroll
        for (int tk = 0; tk < 4; ++tk)
            rv[tk].v = *reinterpret_cast<const float4*>(sm + (4 + kG + 8 * tk) * PITCH + h4);
#pragma unroll
        for (int tj = 0; tj < 3; ++tj)
            bv[tj].v = *reinterpret_cast<const float4*>(sm + (36 + jG + 8 * tj) * PITCH + h4);

#pragma unroll
        for (int c = 0; c < 4; ++c) {
            const float a = av.f[c], w = wv.f[c];
            float p[4];
#pragma unroll
            for (int tk = 0; tk < 4; ++tk) p[tk] = a + rv[tk].f[c];
#pragma unroll
            for (int tj = 0; tj < 3; ++tj) {
                const float bb = bv[tj].f[c];
#pragma unroll
                for (int tk = 0; tk < 4; ++tk) {
                    float v = p[tk] + bb;
                    v = v > 0.f ? v : 0.f;
                    acc[tj][tk] = fmaf(v, w, acc[tj][tk]);
                }
            }
        }
    }

    float* lp = Lpart + (size_t)blockIdx.z * NTRIP;
    const int i_ = i0 + wave;
#pragma unroll
    for (int tj = 0; tj < 3; ++tj) {
        const int j_ = j0 + jG + 8 * tj;
#pragma unroll
        for (int tk = 0; tk < 4; ++tk) {
            const int k_ = kG + 8 * tk;
            lp[(i_ * Ee + j_) * Rr + k_] = acc[tj][tk];
        }
    }
}

__global__ __launch_bounds__(256) void k3_final(const float* __restrict__ Lpart,
                                                const float* __restrict__ b2,
                                                const int* __restrict__ starts,
                                                const int* __restrict__ maxd,
                                                float* __restrict__ out) {
    const int idx = blockIdx.x * 256 + threadIdx.x;
    float s = b2[0];
#pragma unroll
    for (int z = 0; z < HS; ++z) s += Lpart[(size_t)z * NTRIP + idx];
    const int ij = idx >> 5;
    const int j = ij % Ee;
    const int i = ij / Ee;
    const float sc = 1.f / (1.f + expf(-s));
    int di = starts[i] - starts[j]; if (di < 0) di = -di;
    const bool m = (i != j) && (di <= maxd[0]);
    out[idx] = m ? sc : 0.f;
}

// ============================ launch ============================
extern "C" void kernel_launch(void* const* d_in, const int* in_sizes, int n_in,
                              void* d_out, int out_size, void* d_ws, size_t ws_size,
                              hipStream_t stream) {
    const float* ent    = (const float*)d_in[0];
    const float* rel    = (const float*)d_in[1];
    const float* W1     = (const float*)d_in[2];
    const float* b1     = (const float*)d_in[3];
    const float* W2     = (const float*)d_in[4];
    const float* b2     = (const float*)d_in[5];
    const int*   starts = (const int*)d_in[6];
    const int*   maxd   = (const int*)d_in[7];
    float* out = (float*)d_out;
    char* ws = (char*)d_ws;

    const size_t ppartB = (size_t)FSc * NROWS * Hh * 4;      // 16.78 MB (> Lpart 9.44 MB)
    const size_t tB = (size_t)NROWS * Hh * 4;                // 0.52 MB
    const size_t cntOff = (size_t)48 << 20;                  // counter at ws+48MB

    if (ws_size >= cntOff + 64) {
        float* Ppart = (float*)ws;
        float* Lpart = (float*)ws;                  // reuses Ppart region after phase 1b
        float* T     = (float*)(ws + ppartB);
        unsigned* cnt = (unsigned*)(ws + cntOff);

        hipMemsetAsync(cnt, 0, 64, stream);         // reset barrier counter each launch
        fused_bar<<<256, 256, 0, stream>>>(ent, rel, W1, b1, W2, b2, starts, maxd,
                                           Ppart, T, Lpart, out, cnt);
    } else {
        // legacy 4-kernel fallback for small workspaces
        const size_t lpartB = (size_t)HS * NTRIP * 4;
        int FS = 8;
        while (FS > 2) {
            const size_t pB = (size_t)FS * NROWS * Hh * 4;
            const size_t regionA = (pB > lpartB) ? pB : lpartB;
            if (regionA + tB <= ws_size) break;
            FS >>= 1;
        }
        const size_t pB = (size_t)FS * NROWS * Hh * 4;
        const size_t regionA = (pB > lpartB) ? pB : lpartB;

        float* Ppart = (float*)ws;
        float* Lpart = (float*)ws;
        float* T     = (float*)(ws + regionA);

        const int fcount = Hh / FS;
        k1_gemm<<<dim3(8, FS), 256, 16 * fcount * 4, stream>>>(ent, rel, W1, Ppart, fcount);
        k1b_reduce<<<(NROWS * Hh) / 256, 256, 0, stream>>>(Ppart, b1, T, FS);
        k2_triplets<<<dim3(12, 2, HS), 256, 0, stream>>>(T, W2, Lpart);
        k3_final<<<NTRIP / 256, 256, 0, stream>>>(Lpart, b2, starts, maxd, out);
    }
}

// Round 5
// 29.341 us; speedup vs baseline: 5.2307x; 4.1469x over previous
//
#include <hip/hip_runtime.h>
#include <hip/hip_bf16.h>
#include <math.h>

// Problem constants: H=1024, E=48, R=32
#define Hh 1024
#define Ee 48
#define Rr 32
#define PITCH_A 1028            // emb LDS pitch (floats): 1028%32=4 -> rsub groups ~2-way (free)
#define PITCH_B 516             // kB row pitch: 516%32=4 -> row-index -> bank-quad spread

union F4 { float4 v; float f[4]; };

// ================= kA: T[128][1024] = emb @ W1seg (+b1 on rel rows) =================
// grid 256 (rt = b&7: 16 rows; ht = b>>3: 32 h), block 512 (8 waves).
// wave w owns f-range [w*128, w*128+128); lane: h4g=lane&7 (4 h), rsub=lane>>3 (2 rows).
// Partial sums reduced across waves via LDS.
__global__ __launch_bounds__(512) void kA_table(const float* __restrict__ ent,
                                                const float* __restrict__ rel,
                                                const float* __restrict__ W1,
                                                const float* __restrict__ b1,
                                                float* __restrict__ T) {
    __shared__ float se[16 * PITCH_A];      // 64.3 KB; reused for partials
    const int tid = threadIdx.x;
    const int rt = blockIdx.x & 7;
    const int h0 = (blockIdx.x >> 3) * 32;
    const int row0 = rt * 16;

    const float* emb; int foff;
    if (row0 < 48)      { emb = ent + row0 * Hh;        foff = 0;      }
    else if (row0 < 80) { emb = rel + (row0 - 48) * Hh; foff = Hh;     }
    else                { emb = ent + (row0 - 80) * Hh; foff = 2 * Hh; }

    // stage 16 emb rows (64KB), f4-coalesced
    for (int q = 0; q < 8; ++q) {
        const int id4 = tid + q * 512;              // 0..4095 (16 rows x 256 f4)
        const int r = id4 >> 8, o4 = id4 & 255;
        *reinterpret_cast<float4*>(&se[r * PITCH_A + o4 * 4]) =
            *reinterpret_cast<const float4*>(&emb[r * Hh + o4 * 4]);
    }
    __syncthreads();

    const int w    = tid >> 6;
    const int lane = tid & 63;
    const int h4g  = lane & 7;
    const int rsub = lane >> 3;
    const int r0 = rsub * 2, r1 = r0 + 1;
    const int fb = w * 128;

    const float* w1p = W1 + (size_t)(foff + fb) * Hh + h0 + h4g * 4;
    const float* e0p = se + r0 * PITCH_A + fb;
    const float* e1p = se + r1 * PITCH_A + fb;

    float acc[2][4];
#pragma unroll
    for (int a = 0; a < 2; ++a)
#pragma unroll
        for (int c = 0; c < 4; ++c) acc[a][c] = 0.f;

    F4 wk[4];
#pragma unroll
    for (int c = 0; c < 4; ++c)
        wk[c].v = *reinterpret_cast<const float4*>(w1p + (size_t)c * Hh);

    for (int s = 0; s < 32; ++s) {
        const int f = s * 4;
        F4 wn[4];
        if (s < 31) {
#pragma unroll
            for (int c = 0; c < 4; ++c)
                wn[c].v = *reinterpret_cast<const float4*>(w1p + (size_t)(f + 4 + c) * Hh);
        }
        F4 e0, e1;
        e0.v = *reinterpret_cast<const float4*>(e0p + f);
        e1.v = *reinterpret_cast<const float4*>(e1p + f);
#pragma unroll
        for (int c = 0; c < 4; ++c) {
#pragma unroll
            for (int hh = 0; hh < 4; ++hh) {
                acc[0][hh] = fmaf(e0.f[c], wk[c].f[hh], acc[0][hh]);
                acc[1][hh] = fmaf(e1.f[c], wk[c].f[hh], acc[1][hh]);
            }
        }
        if (s < 31) {
#pragma unroll
            for (int c = 0; c < 4; ++c) wk[c] = wn[c];
        }
    }

    // reduce 8 wave-partials via LDS (reuse se region)
    __syncthreads();
    {
        float* part = se;                    // [8 waves][64 lanes][8]
        const int base = (w * 64 + lane) * 8;
        F4 o0, o1;
#pragma unroll
        for (int c = 0; c < 4; ++c) { o0.f[c] = acc[0][c]; o1.f[c] = acc[1][c]; }
        *reinterpret_cast<float4*>(&part[base])     = o0.v;
        *reinterpret_cast<float4*>(&part[base + 4]) = o1.v;
    }
    __syncthreads();
    {
        // tid -> output (r = tid>>5, h = tid&31)
        const int r = tid >> 5, h = tid & 31;
        const int src = ((r >> 1) * 8 + (h >> 2)) * 8 + (r & 1) * 4 + (h & 3);
        float s = 0.f;
#pragma unroll
        for (int ww = 0; ww < 8; ++ww) s += se[ww * 512 + src];
        const int row = row0 + r;
        if (row >= 48 && row < 80) s += b1[h0 + h];
        T[row * Hh + h0 + h] = s;
    }
}

// ================= kB: triplet logits over full h, sigmoid+mask, write out =================
// grid 192 (i = b>>2, js = (b>>1)&1, ks = b&1), block 512 (8 waves).
// LDS rows: [A(1) | R(16) | B(24) | W2] x 512-h chunk (pitch 516). 2 chunks cover h=1024.
// wave w handles h-slice w*64 within each chunk; lane: jG=lane&7 (3 j), kG=lane>>3 (2 k).
__global__ __launch_bounds__(512) void kB_triplets(const float* __restrict__ T,
                                                   const float* __restrict__ W2,
                                                   const float* __restrict__ b2,
                                                   const int* __restrict__ starts,
                                                   const int* __restrict__ maxd,
                                                   float* __restrict__ out) {
    __shared__ float se[42 * PITCH_B];      // 84.7 KB; reused for partials
    const int tid = threadIdx.x;
    const int i  = blockIdx.x >> 2;
    const int js = (blockIdx.x >> 1) & 1;
    const int ks = blockIdx.x & 1;
    const int j0 = js * 24;
    const int k0 = ks * 16;

    const int w    = tid >> 6;
    const int lane = tid & 63;
    const int jG = lane & 7;
    const int kG = lane >> 3;

    float acc[3][2];
#pragma unroll
    for (int a = 0; a < 3; ++a) { acc[a][0] = 0.f; acc[a][1] = 0.f; }

    for (int c = 0; c < 2; ++c) {
        const int hbase = c * 512;
        // stage 41 T-rows + W2 slice (f4-coalesced): 42 x 128 f4
        __syncthreads();
        for (int q = 0; q < 11; ++q) {
            const int id4 = tid + q * 512;
            if (id4 < 5376) {
                const int g = id4 >> 7, o4 = id4 & 127;
                const float* src;
                if (g == 41) src = W2 + hbase + o4 * 4;
                else {
                    int grow;
                    if (g == 0)       grow = i;                   // A row (subject)
                    else if (g < 17)  grow = 48 + k0 + (g - 1);   // R rows
                    else              grow = 80 + j0 + (g - 17);  // B rows (object)
                    src = T + grow * Hh + hbase + o4 * 4;
                }
                *reinterpret_cast<float4*>(&se[g * PITCH_B + o4 * 4]) =
                    *reinterpret_cast<const float4*>(src);
            }
        }
        __syncthreads();

        const int hw = w * 64;               // wave's 64-h slice within chunk
        const float* pa = se + hw;
        const float* pw = se + 41 * PITCH_B + hw;

#pragma unroll
        for (int s = 0; s < 16; ++s) {
            const int h4 = s * 4;
            F4 av, wv, rv[2], bv[3];
            av.v = *reinterpret_cast<const float4*>(pa + h4);
            wv.v = *reinterpret_cast<const float4*>(pw + h4);
#pragma unroll
            for (int tk = 0; tk < 2; ++tk)
                rv[tk].v = *reinterpret_cast<const float4*>(se + (1 + kG + 8 * tk) * PITCH_B + hw + h4);
#pragma unroll
            for (int tj = 0; tj < 3; ++tj)
                bv[tj].v = *reinterpret_cast<const float4*>(se + (17 + jG + 8 * tj) * PITCH_B + hw + h4);

#pragma unroll
            for (int cc = 0; cc < 4; ++cc) {
                const float a = av.f[cc], w2v = wv.f[cc];
                const float p0 = a + rv[0].f[cc];
                const float p1 = a + rv[1].f[cc];
#pragma unroll
                for (int tj = 0; tj < 3; ++tj) {
                    const float bb = bv[tj].f[cc];
                    float v0 = p0 + bb; v0 = v0 > 0.f ? v0 : 0.f;
                    acc[tj][0] = fmaf(v0, w2v, acc[tj][0]);
                    float v1 = p1 + bb; v1 = v1 > 0.f ? v1 : 0.f;
                    acc[tj][1] = fmaf(v1, w2v, acc[tj][1]);
                }
            }
        }
    }

    // cross-wave reduce (8 h-slices hold the same 384 triplets), then finalize
    __syncthreads();
    {
        float* part = se;                    // [8][384]
#pragma unroll
        for (int tj = 0; tj < 3; ++tj)
#pragma unroll
            for (int tk = 0; tk < 2; ++tk)
                part[w * 384 + (tj * 8 + jG) * 16 + tk * 8 + kG] = acc[tj][tk];
    }
    __syncthreads();
    if (tid < 384) {
        float s = b2[0];
#pragma unroll
        for (int ww = 0; ww < 8; ++ww) s += se[ww * 384 + tid];
        const int jl = tid >> 4, kl = tid & 15;
        const int j = j0 + jl, k = k0 + kl;
        const float sc = 1.f / (1.f + expf(-s));
        int di = starts[i] - starts[j]; if (di < 0) di = -di;
        const bool m = (i != j) && (di <= maxd[0]);
        out[(i * Ee + j) * Rr + k] = m ? sc : 0.f;
    }
}

// ============================ launch ============================
extern "C" void kernel_launch(void* const* d_in, const int* in_sizes, int n_in,
                              void* d_out, int out_size, void* d_ws, size_t ws_size,
                              hipStream_t stream) {
    const float* ent    = (const float*)d_in[0];
    const float* rel    = (const float*)d_in[1];
    const float* W1     = (const float*)d_in[2];
    const float* b1     = (const float*)d_in[3];
    const float* W2     = (const float*)d_in[4];
    const float* b2     = (const float*)d_in[5];
    const int*   starts = (const int*)d_in[6];
    const int*   maxd   = (const int*)d_in[7];
    float* out = (float*)d_out;

    float* T = (float*)d_ws;                 // 128 x 1024 floats = 512 KB

    kA_table<<<256, 512, 0, stream>>>(ent, rel, W1, b1, T);
    kB_triplets<<<192, 512, 0, stream>>>(T, W2, b2, starts, maxd, out);
}